// Round 10
// baseline (412.428 us; speedup 1.0000x reference)
//
#include <hip/hip_runtime.h>

typedef unsigned short u16;
typedef unsigned int u32;

#define B_ 4
#define S_ 1024
#define D_ 1024
#define H_ 16
#define DH_ 64
#define FF_ 4096
#define M_ 4096
#define SCALE_ 0.125f

typedef __attribute__((ext_vector_type(8))) __bf16 bf16x8;
typedef __attribute__((ext_vector_type(4))) float f32x4;

__device__ __forceinline__ f32x4 mfma16(bf16x8 a, bf16x8 b, f32x4 c) {
  return __builtin_amdgcn_mfma_f32_16x16x32_bf16(a, b, c, 0, 0, 0);
}

// native converts -> compiler emits v_cvt_pk_bf16_f32 (catalog m240)
__device__ __forceinline__ u16 f2bf(float x) {
  union { __bf16 h; u16 u; } cv; cv.h = (__bf16)x; return cv.u;
}
__device__ __forceinline__ float bf2f(u16 u) {
  union { u32 u; float f; } cv; cv.u = ((u32)u) << 16; return cv.f;
}
__device__ __forceinline__ u32 packbf2(float a, float b) {
  union { u32 u; __bf16 h[2]; } pk;
  pk.h[0] = (__bf16)a; pk.h[1] = (__bf16)b;
  return pk.u;
}
__device__ __forceinline__ float gelu_exact(float x) {
  return 0.5f * x * (1.f + erff(x * 0.7071067811865475f));
}
__device__ __forceinline__ void gload16(const void* g, void* l) {
  __builtin_amdgcn_global_load_lds((__attribute__((address_space(1))) void*)(g),
                                   (__attribute__((address_space(3))) void*)(l),
                                   16, 0, 0);
}

// ===========================================================================
// 128x128 GEMM, 4 waves (2x2), BK=64, dbuf 64KiB LDS — round-6 schedule
// (best known for the small/odd shapes). Split-K via blockIdx.z. EPI:
//   0 = permuted bf16 -> [ts][B,H,S,DH], ts==0 plane scaled 0.125 (QKV)
//   1 = f32 out = res + acc + bias
//   2 = bf16 gelu(acc+bias)        3 = bf16 (acc+bias)*bf2f(aux)
//   4 = bf16 raw partial -> out[z*M*N + m*N + n]
//   5 = permuted bf16, NO scale (KV fused store)
// ===========================================================================
template<int EPI>
__global__ __launch_bounds__(256, 2) void gemm128(
    const u16* __restrict__ A, const u16* __restrict__ BT,
    const float* __restrict__ bias, const float* __restrict__ res,
    const u16* __restrict__ aux, void* __restrict__ out,
    int M, int N, int K, int ktiles)
{
  __shared__ u16 As[2][128 * 64];
  __shared__ u16 Bs[2][128 * 64];

  const int tid = threadIdx.x;
  const int wave = tid >> 6, lane = tid & 63;
  const int wm = wave >> 1, wn = wave & 1;
  const int qi = lane & 15, g = lane >> 4;

  const int gx = N >> 7;
  const int nwg = gx * (M >> 7);
  int id = blockIdx.y * gridDim.x + blockIdx.x;
  id = (id & 7) * (nwg >> 3) + (id >> 3);      // XCD swizzle (nwg % 8 == 0)
  const int m0 = (id / gx) << 7, n0 = (id % gx) << 7;

  const int NT = ktiles;
  const int kbase = blockIdx.z * ktiles * 64;

  const int r0 = tid >> 3;
  const int scol = (((tid & 7) ^ ((tid >> 3) & 7)) << 3);
  const int swb = wave << 6;

  f32x4 acc[4][4];
#pragma unroll
  for (int i = 0; i < 4; ++i)
#pragma unroll
    for (int j = 0; j < 4; ++j)
      acc[i][j] = (f32x4){0.f, 0.f, 0.f, 0.f};

#define STAGE_A(t, h, b) {                                                  \
    const int tt = (t) >= NT ? (t) - NT : (t);                              \
    _Pragma("unroll")                                                       \
    for (int i = 0; i < 2; ++i) {                                           \
      const int r = (h) * 64 + i * 32 + r0;                                 \
      gload16(A + (size_t)(m0 + r) * K + kbase + tt * 64 + scol,            \
              &As[b][(h) * 4096 + (i * 256 + swb) * 8]);                    \
    } }
#define STAGE_B(t, h, b) {                                                  \
    const int tt = (t) >= NT ? (t) - NT : (t);                              \
    _Pragma("unroll")                                                       \
    for (int i = 0; i < 2; ++i) {                                           \
      const int r = (h) * 64 + i * 32 + r0;                                 \
      gload16(BT + (size_t)(n0 + r) * K + kbase + tt * 64 + scol,           \
              &Bs[b][(h) * 4096 + (i * 256 + swb) * 8]);                    \
    } }

  bf16x8 af[4][2], bfr[4][2];

#define RD_ALL(b)                                                            \
  _Pragma("unroll") for (int mi = 0; mi < 4; ++mi)                           \
  _Pragma("unroll") for (int kk = 0; kk < 2; ++kk) {                         \
    const int row = wm * 64 + mi * 16 + qi;                                  \
    const int cb = ((kk * 64 + (g << 4)) ^ ((qi & 7) << 4));                 \
    af[mi][kk] = *(const bf16x8*)((const char*)&As[b][0] + row * 128 + cb);  \
  }                                                                          \
  _Pragma("unroll") for (int ni = 0; ni < 4; ++ni)                           \
  _Pragma("unroll") for (int kk = 0; kk < 2; ++kk) {                         \
    const int row = wn * 64 + ni * 16 + qi;                                  \
    const int cb = ((kk * 64 + (g << 4)) ^ ((qi & 7) << 4));                 \
    bfr[ni][kk] = *(const bf16x8*)((const char*)&Bs[b][0] + row * 128 + cb); \
  }

#define HALF(milo)                                                           \
  _Pragma("unroll") for (int mi = (milo); mi < (milo) + 2; ++mi)             \
  _Pragma("unroll") for (int ni = 0; ni < 4; ++ni)                           \
  _Pragma("unroll") for (int kk = 0; kk < 2; ++kk)                           \
    acc[mi][ni] = mfma16(af[mi][kk], bfr[ni][kk], acc[mi][ni]);

#define BAR() __builtin_amdgcn_s_barrier()
#define LGKM0() { asm volatile("s_waitcnt lgkmcnt(0)" ::: "memory");         \
                  __builtin_amdgcn_sched_barrier(0); }
#define VM8() asm volatile("s_waitcnt vmcnt(8)" ::: "memory")
#define PRIO(x) __builtin_amdgcn_s_setprio(x)

  STAGE_A(0, 0, 0); STAGE_A(0, 1, 0); STAGE_B(0, 0, 0); STAGE_B(0, 1, 0);
  STAGE_A(1, 0, 1); STAGE_A(1, 1, 1); STAGE_B(1, 0, 1); STAGE_B(1, 1, 1);
  VM8();
  BAR();

  const int NI = NT >> 1;
  for (int it = 0; it < NI; ++it) {
    const int k = it * 2;
    RD_ALL(0); LGKM0();
    BAR();
    STAGE_A(k + 2, 0, 0); STAGE_A(k + 2, 1, 0);
    PRIO(1); HALF(0); PRIO(0);
    STAGE_B(k + 2, 0, 0); STAGE_B(k + 2, 1, 0);
    PRIO(1); HALF(2); PRIO(0);
    VM8();
    BAR();
    RD_ALL(1); LGKM0();
    BAR();
    STAGE_A(k + 3, 0, 1); STAGE_A(k + 3, 1, 1);
    PRIO(1); HALF(0); PRIO(0);
    STAGE_B(k + 3, 0, 1); STAGE_B(k + 3, 1, 1);
    PRIO(1); HALF(2); PRIO(0);
    VM8();
    BAR();
  }

#pragma unroll
  for (int mi = 0; mi < 4; ++mi) {
#pragma unroll
    for (int ni = 0; ni < 4; ++ni) {
#pragma unroll
      for (int r = 0; r < 4; ++r) {
        const int m = m0 + wm * 64 + mi * 16 + g * 4 + r;
        const int n = n0 + wn * 64 + ni * 16 + qi;
        float v = acc[mi][ni][r];
        if (EPI == 0 || EPI == 5) {
          const int ts = n >> 10, b = m >> 10, s = m & 1023;
          const int hh = (n >> 6) & 15, dh = n & 63;
          if (EPI == 0 && ts == 0) v *= SCALE_;
          ((u16*)out)[(size_t)ts * (B_ * H_ * S_ * DH_) +
                      (((size_t)(b * H_ + hh) * S_) + s) * DH_ + dh] = f2bf(v);
        } else if (EPI == 1) {
          const size_t idx = (size_t)m * N + n;
          ((float*)out)[idx] = res[idx] + v + bias[n];
        } else if (EPI == 2) {
          ((u16*)out)[(size_t)m * N + n] = f2bf(gelu_exact(v + bias[n]));
        } else if (EPI == 3) {
          const size_t idx = (size_t)m * N + n;
          ((u16*)out)[idx] = f2bf((v + bias[n]) * bf2f(aux[idx]));
        } else {
          const size_t idx = (size_t)blockIdx.z * ((size_t)M * N) +
                             (size_t)m * N + n;
          ((u16*)out)[idx] = f2bf(v);
        }
      }
    }
  }
#undef STAGE_A
#undef STAGE_B
#undef RD_ALL
#undef HALF
#undef BAR
#undef LGKM0
#undef VM8
#undef PRIO
}

// ===========================================================================
// 256x256 8-PHASE GEMM with the CORRECTED deep ledger (m201-faithful).
// 512 threads = 8 waves (2M x 4N), per-wave C 128x64, BK=64, 128 KiB LDS.
// Buffer-free analysis: buf-B frees after ph2, buf-A after ph3. Staging slots:
//   ph1,2: A(t1)->buf1 ; ph3,4: B(t0+2)->buf0 ; ph5,6: A(t0+2)->buf0 ;
//   ph7,8: B(t1+2)->buf1.   vmcnt(4) ONLY at ph4/ph8 (6 half-tiles
//   outstanding, drain to 2) -> every tile lands 4-6 phases before its read.
// Prologue: A(0),B(0),B(1) = 12 loads; vmcnt(4). Each phase: {ds_read quad |
// 1 stage} ; BAR ; lgkmcnt(0)+sched_barrier ; setprio(1) 16 MFMA setprio(0) ;
// [vmcnt(4)] ; BAR.  T2 XOR swizzle both-sides. Split-K via blockIdx.z.
// EPI: 2 = bf16 gelu(acc+bias); 3 = bf16 (acc+bias)*bf2f(aux); 4 = partial.
// ===========================================================================
template<int EPI>
__global__ __launch_bounds__(512, 2) void gemm256p(
    const u16* __restrict__ A, const u16* __restrict__ BT,
    const float* __restrict__ bias, const float* __restrict__ res,
    const u16* __restrict__ aux, void* __restrict__ out,
    int M, int N, int K, int ktiles)
{
  __shared__ u16 As[2][256 * 64];
  __shared__ u16 Bs[2][256 * 64];

  const int tid = threadIdx.x;
  const int wave = tid >> 6, lane = tid & 63;
  const int wm = wave >> 2, wn = wave & 3;
  const int qi = lane & 15, g = lane >> 4;

  const int gx = N >> 8;
  const int nwg = gx * (M >> 8);
  int id = blockIdx.y * gridDim.x + blockIdx.x;
  id = (id & 7) * (nwg >> 3) + (id >> 3);      // XCD swizzle (nwg % 8 == 0)
  const int m0 = (id / gx) << 8, n0 = (id % gx) << 8;

  const int NT = ktiles;
  const int kbase = blockIdx.z * ktiles * 64;

  // half-tile staging: 128 rows x 64 cols = 2 gload rounds of 512 threads
  const int srow = tid >> 3;                                  // 0..63
  const int scol = (((tid & 7) ^ ((tid >> 3) & 7)) << 3);     // elements
  const int sldsb = wave << 9;                                // wave*512 u16

  f32x4 acc[8][4];
#pragma unroll
  for (int i = 0; i < 8; ++i)
#pragma unroll
    for (int j = 0; j < 4; ++j)
      acc[i][j] = (f32x4){0.f, 0.f, 0.f, 0.f};

#define SA(t, h, b) {                                                       \
    const int tt = (t) >= NT ? (t) - NT : (t);                              \
    _Pragma("unroll")                                                       \
    for (int i = 0; i < 2; ++i) {                                           \
      const int r = (h) * 128 + i * 64 + srow;                              \
      gload16(A + (size_t)(m0 + r) * K + kbase + tt * 64 + scol,            \
              &As[b][(h) * 8192 + i * 4096 + sldsb]);                       \
    } }
#define SB(t, h, b) {                                                       \
    const int tt = (t) >= NT ? (t) - NT : (t);                              \
    _Pragma("unroll")                                                       \
    for (int i = 0; i < 2; ++i) {                                           \
      const int r = (h) * 128 + i * 64 + srow;                              \
      gload16(BT + (size_t)(n0 + r) * K + kbase + tt * 64 + scol,           \
              &Bs[b][(h) * 8192 + i * 4096 + sldsb]);                       \
    } }

  bf16x8 af[4][2], bfr[4][2];

#define RD_A(b, mq)                                                          \
  _Pragma("unroll") for (int mi = 0; mi < 4; ++mi)                           \
  _Pragma("unroll") for (int kk = 0; kk < 2; ++kk) {                         \
    const int row = wm * 128 + (mq) * 64 + mi * 16 + qi;                     \
    const int cb = ((kk * 64 + (g << 4)) ^ ((qi & 7) << 4));                 \
    af[mi][kk] = *(const bf16x8*)((const char*)&As[b][0] + row * 128 + cb);  \
  }
#define RD_B(b, nq)                                                          \
  _Pragma("unroll") for (int ni = 0; ni < 2; ++ni)                           \
  _Pragma("unroll") for (int kk = 0; kk < 2; ++kk) {                         \
    const int row = wn * 64 + (nq) * 32 + ni * 16 + qi;                      \
    const int cb = ((kk * 64 + (g << 4)) ^ ((qi & 7) << 4));                 \
    bfr[(nq) * 2 + ni][kk] =                                                 \
        *(const bf16x8*)((const char*)&Bs[b][0] + row * 128 + cb);           \
  }
#define QUAD(mq, nq)                                                         \
  _Pragma("unroll") for (int mi = 0; mi < 4; ++mi)                           \
  _Pragma("unroll") for (int ni = 0; ni < 2; ++ni)                           \
  _Pragma("unroll") for (int kk = 0; kk < 2; ++kk)                           \
    acc[(mq) * 4 + mi][(nq) * 2 + ni] =                                      \
        mfma16(af[mi][kk], bfr[(nq) * 2 + ni][kk],                           \
               acc[(mq) * 4 + mi][(nq) * 2 + ni]);

#define BAR() __builtin_amdgcn_s_barrier()
#define LGKM0() { asm volatile("s_waitcnt lgkmcnt(0)" ::: "memory");         \
                  __builtin_amdgcn_sched_barrier(0); }
#define VM4() asm volatile("s_waitcnt vmcnt(4)" ::: "memory")
#define PRIO(x) __builtin_amdgcn_s_setprio(x)

  // prologue: tile0 A+B, tile1 B (12 loads); vmcnt(4) -> tile0 landed
  SA(0, 0, 0); SA(0, 1, 0); SB(0, 0, 0); SB(0, 1, 0);
  SB(1, 0, 1); SB(1, 1, 1);
  VM4();
  BAR();

  const int NI = NT >> 1;
  for (int it = 0; it < NI; ++it) {
    const int t0 = it * 2, t1 = t0 + 1;
    // ---- phases 1-4: K-tile t0 (buf0) ----
    RD_A(0, 0); RD_B(0, 0); SA(t1, 0, 1);
    BAR(); LGKM0(); PRIO(1); QUAD(0, 0); PRIO(0); BAR();

    RD_B(0, 1); SA(t1, 1, 1);
    BAR(); LGKM0(); PRIO(1); QUAD(0, 1); PRIO(0); BAR();

    RD_A(0, 1); SB(t0 + 2, 0, 0);
    BAR(); LGKM0(); PRIO(1); QUAD(1, 0); PRIO(0); BAR();

    SB(t0 + 2, 1, 0);
    BAR(); PRIO(1); QUAD(1, 1); PRIO(0); VM4(); BAR();

    // ---- phases 5-8: K-tile t1 (buf1) ----
    RD_A(1, 0); RD_B(1, 0); SA(t0 + 2, 0, 0);
    BAR(); LGKM0(); PRIO(1); QUAD(0, 0); PRIO(0); BAR();

    RD_B(1, 1); SA(t0 + 2, 1, 0);
    BAR(); LGKM0(); PRIO(1); QUAD(0, 1); PRIO(0); BAR();

    RD_A(1, 1); SB(t1 + 2, 0, 1);
    BAR(); LGKM0(); PRIO(1); QUAD(1, 0); PRIO(0); BAR();

    SB(t1 + 2, 1, 1);
    BAR(); PRIO(1); QUAD(1, 1); PRIO(0); VM4(); BAR();
  }

#pragma unroll
  for (int mi = 0; mi < 8; ++mi) {
#pragma unroll
    for (int ni = 0; ni < 4; ++ni) {
#pragma unroll
      for (int r = 0; r < 4; ++r) {
        const int m = m0 + wm * 128 + mi * 16 + g * 4 + r;
        const int n = n0 + wn * 64 + ni * 16 + qi;
        const float v = acc[mi][ni][r];
        if (EPI == 2) {
          ((u16*)out)[(size_t)m * N + n] = f2bf(gelu_exact(v + bias[n]));
        } else if (EPI == 3) {
          const size_t idx = (size_t)m * N + n;
          ((u16*)out)[idx] = f2bf((v + bias[n]) * bf2f(aux[idx]));
        } else {
          const size_t idx = (size_t)blockIdx.z * ((size_t)M * N) +
                             (size_t)m * N + n;
          ((u16*)out)[idx] = f2bf(v);
        }
      }
    }
  }
#undef SA
#undef SB
#undef RD_A
#undef RD_B
#undef QUAD
#undef BAR
#undef LGKM0
#undef VM4
#undef PRIO
}

// ---------------------------------------------------------------------------
// Split-K reduce + residual + bias (f32 out), optional fused LayerNorm.
// ---------------------------------------------------------------------------
template<bool DOLN, int NS>
__global__ __launch_bounds__(256) void reduce_ln(
    const u16* __restrict__ p, const float* __restrict__ bias,
    const float* __restrict__ res, float* __restrict__ outf,
    const float* __restrict__ gg, const float* __restrict__ bb,
    u16* __restrict__ outn)
{
  __shared__ float red[8];
  const int row = blockIdx.x, tid = threadIdx.x;
  const size_t base = (size_t)row * 1024 + tid * 4;
  const size_t total = (size_t)M_ * 1024;
  float a0 = 0.f, a1 = 0.f, a2 = 0.f, a3 = 0.f;
#pragma unroll
  for (int s = 0; s < NS; ++s) {
    const uint2 u = *(const uint2*)&p[(size_t)s * total + base];
    a0 += bf2f((u16)(u.x & 0xffff));
    a1 += bf2f((u16)(u.x >> 16));
    a2 += bf2f((u16)(u.y & 0xffff));
    a3 += bf2f((u16)(u.y >> 16));
  }
  const float4 b4 = ((const float4*)bias)[tid];
  const float4 r4 = *(const float4*)&res[base];
  float4 o;
  o.x = r4.x + a0 + b4.x;
  o.y = r4.y + a1 + b4.y;
  o.z = r4.z + a2 + b4.z;
  o.w = r4.w + a3 + b4.w;
  *(float4*)&outf[base] = o;

  if (DOLN) {
    float s1 = o.x + o.y + o.z + o.w;
    float s2 = o.x * o.x + o.y * o.y + o.z * o.z + o.w * o.w;
#pragma unroll
    for (int m = 32; m; m >>= 1) {
      s1 += __shfl_xor(s1, m);
      s2 += __shfl_xor(s2, m);
    }
    const int wave = tid >> 6, lane = tid & 63;
    if (lane == 0) { red[wave * 2] = s1; red[wave * 2 + 1] = s2; }
    __syncthreads();
    const float St = red[0] + red[2] + red[4] + red[6];
    const float SQt = red[1] + red[3] + red[5] + red[7];
    const float mean = St * (1.f / 1024.f);
    float var = SQt * (1.f / 1024.f) - mean * mean;
    var = fmaxf(var, 0.f);
    const float rinv = rsqrtf(var + 1e-12f);
    const float4 g4 = ((const float4*)gg)[tid];
    const float4 bb4 = ((const float4*)bb)[tid];
    uint2 w;
    w.x = packbf2((o.x - mean) * rinv * g4.x + bb4.x,
                  (o.y - mean) * rinv * g4.y + bb4.y);
    w.y = packbf2((o.z - mean) * rinv * g4.z + bb4.z,
                  (o.w - mean) * rinv * g4.w + bb4.w);
    ((uint2*)(outn + (size_t)row * 1024))[tid] = w;
  }
}

// ---------------------------------------------------------------------------
template<int NS, bool QSC>
__global__ __launch_bounds__(256) void reduce_perm(
    const u16* __restrict__ p, u16* __restrict__ out, int M, int N)
{
  const size_t flat = ((size_t)blockIdx.x * 256 + threadIdx.x) * 4;
  const size_t total = (size_t)M * N;
  float a0 = 0.f, a1 = 0.f, a2 = 0.f, a3 = 0.f;
#pragma unroll
  for (int s = 0; s < NS; ++s) {
    const uint2 u = *(const uint2*)&p[(size_t)s * total + flat];
    a0 += bf2f((u16)(u.x & 0xffff));
    a1 += bf2f((u16)(u.x >> 16));
    a2 += bf2f((u16)(u.y & 0xffff));
    a3 += bf2f((u16)(u.y >> 16));
  }
  if (QSC) { a0 *= SCALE_; a1 *= SCALE_; a2 *= SCALE_; a3 *= SCALE_; }
  const int m = (int)(flat / N), nb = (int)(flat % N);
  const int ts = nb >> 10, hh = (nb >> 6) & 15, dh = nb & 63;
  const int b = m >> 10, sI = m & 1023;
  uint2 w;
  w.x = packbf2(a0, a1);
  w.y = packbf2(a2, a3);
  *(uint2*)&out[(size_t)ts * (B_ * H_ * S_ * DH_) +
                (((size_t)(b * H_ + hh) * S_) + sI) * DH_ + dh] = w;
}

// ---------------------------------------------------------------------------
// Flash attention. Q pre-scaled by 0.125. Fixed-max softmax. 4 waves x 16 q.
// ---------------------------------------------------------------------------
template<bool MASKED>
__global__ __launch_bounds__(256, 4) void attn_kernel(
    const u16* __restrict__ Q, const u16* __restrict__ Kb,
    const u16* __restrict__ VT, const float* __restrict__ bias,
    u16* __restrict__ O, int S, int T)
{
  __shared__ u16 Ks[64 * 72];
  __shared__ u16 VTs[64 * 72];
  __shared__ u16 Ps[4][16 * 72];
  __shared__ float biasS[64];

  const int bh = blockIdx.y;
  const int b = bh >> 4, h = bh & 15;
  const int tid = threadIdx.x;
  const int wave = tid >> 6, lane = tid & 63;
  const int g = lane >> 4, qi = lane & 15;
  const int q0w = blockIdx.x * 64 + wave * 16;

  const u16* Qb = Q + (size_t)bh * S * DH_;
  const u16* Kg = Kb + (size_t)bh * T * DH_;
  const u16* Vg = VT + (size_t)bh * DH_ * T;

  bf16x8 qf[2];
  qf[0] = *(const bf16x8*)&Qb[(q0w + qi) * DH_ + g * 8];
  qf[1] = *(const bf16x8*)&Qb[(q0w + qi) * DH_ + 32 + g * 8];

  f32x4 acc[4];
#pragma unroll
  for (int i = 0; i < 4; ++i) acc[i] = (f32x4){0.f, 0.f, 0.f, 0.f};
  float l_run = 1e-30f;

  u16* Pw = &Ps[wave][0];

  for (int t0 = 0; t0 < T; t0 += 64) {
    __syncthreads();
#pragma unroll
    for (int i = 0; i < 2; ++i) {
      const int flat = i * 256 + tid;
      const int row = flat >> 3, kc = flat & 7;
      *(uint4*)&Ks[row * 72 + kc * 8] = *(const uint4*)&Kg[(size_t)(t0 + row) * DH_ + kc * 8];
      *(uint4*)&VTs[row * 72 + kc * 8] = *(const uint4*)&Vg[(size_t)row * T + t0 + kc * 8];
    }
    if (MASKED && tid < 64) biasS[tid] = bias[b * T + t0 + tid];
    __syncthreads();

    f32x4 sacc[4];
#pragma unroll
    for (int nt = 0; nt < 4; ++nt) sacc[nt] = (f32x4){0.f, 0.f, 0.f, 0.f};
#pragma unroll
    for (int kk = 0; kk < 2; ++kk) {
#pragma unroll
      for (int nt = 0; nt < 4; ++nt) {
        bf16x8 kf = *(const bf16x8*)&Ks[(nt * 16 + qi) * 72 + kk * 32 + g * 8];
        sacc[nt] = mfma16(kf, qf[kk], sacc[nt]);
      }
    }
    float p[4][4];
    float lsum = 0.f;
#pragma unroll
    for (int nt = 0; nt < 4; ++nt)
#pragma unroll
      for (int r = 0; r < 4; ++r) {
        float v = sacc[nt][r];
        if (MASKED) v += biasS[nt * 16 + g * 4 + r];
        const float e = __expf(v);
        p[nt][r] = e;
        lsum += e;
      }
    lsum += __shfl_xor(lsum, 16);
    lsum += __shfl_xor(lsum, 32);
    l_run += lsum;

#pragma unroll
    for (int nt = 0; nt < 4; ++nt) {
      uint2 w;
      w.x = packbf2(p[nt][0], p[nt][1]);
      w.y = packbf2(p[nt][2], p[nt][3]);
      *(uint2*)&Pw[qi * 72 + nt * 16 + g * 4] = w;
    }

#pragma unroll
    for (int kk = 0; kk < 2; ++kk) {
      bf16x8 pf = *(const bf16x8*)&Pw[qi * 72 + kk * 32 + g * 8];
#pragma unroll
      for (int ndh = 0; ndh < 4; ++ndh) {
        bf16x8 vf = *(const bf16x8*)&VTs[(ndh * 16 + qi) * 72 + kk * 32 + g * 8];
        acc[ndh] = mfma16(vf, pf, acc[ndh]);
      }
    }
  }

  const float inv = 1.f / l_run;
  const int qg = q0w + qi;
#pragma unroll
  for (int ndh = 0; ndh < 4; ++ndh) {
    uint2 w;
    w.x = packbf2(acc[ndh][0] * inv, acc[ndh][1] * inv);
    w.y = packbf2(acc[ndh][2] * inv, acc[ndh][3] * inv);
    *(uint2*)&O[(size_t)(b * S_ + qg) * D_ + h * DH_ + ndh * 16 + g * 4] = w;
  }
}

// ---------------------------------------------------------------------------
__global__ __launch_bounds__(256) void ln_kernel(
    const float* __restrict__ x, const float* __restrict__ gg,
    const float* __restrict__ bb, u16* __restrict__ out)
{
  __shared__ float red[8];
  const int row = blockIdx.x, tid = threadIdx.x;
  const float4 v = ((const float4*)(x + (size_t)row * D_))[tid];
  float s = v.x + v.y + v.z + v.w;
  float sq = v.x * v.x + v.y * v.y + v.z * v.z + v.w * v.w;
#pragma unroll
  for (int m = 32; m; m >>= 1) {
    s += __shfl_xor(s, m);
    sq += __shfl_xor(sq, m);
  }
  const int wave = tid >> 6, lane = tid & 63;
  if (lane == 0) { red[wave * 2] = s; red[wave * 2 + 1] = sq; }
  __syncthreads();
  const float St = red[0] + red[2] + red[4] + red[6];
  const float SQt = red[1] + red[3] + red[5] + red[7];
  const float mean = St * (1.f / 1024.f);
  float var = SQt * (1.f / 1024.f) - mean * mean;
  var = fmaxf(var, 0.f);
  const float rinv = rsqrtf(var + 1e-12f);
  const float4 g4 = ((const float4*)gg)[tid];
  const float4 b4 = ((const float4*)bb)[tid];
  uint2 o;
  o.x = packbf2((v.x - mean) * rinv * g4.x + b4.x, (v.y - mean) * rinv * g4.y + b4.y);
  o.y = packbf2((v.z - mean) * rinv * g4.z + b4.z, (v.w - mean) * rinv * g4.w + b4.w);
  ((uint2*)(out + (size_t)row * D_))[tid] = o;
}

__global__ __launch_bounds__(256) void transpose_w(
    const float* __restrict__ in, u16* __restrict__ out, int K, int N)
{
  __shared__ float tile[32][33];
  const int tx = threadIdx.x & 31, ty = threadIdx.x >> 5;
  const int k0 = blockIdx.y * 32, n0 = blockIdx.x * 32;
#pragma unroll
  for (int j = 0; j < 4; ++j)
    tile[ty + 8 * j][tx] = in[(size_t)(k0 + ty + 8 * j) * N + n0 + tx];
  __syncthreads();
#pragma unroll
  for (int j = 0; j < 4; ++j)
    out[(size_t)(n0 + ty + 8 * j) * K + k0 + tx] = f2bf(tile[tx][ty + 8 * j]);
}

__global__ __launch_bounds__(256) void transpose_v(
    const u16* __restrict__ in, u16* __restrict__ out, int T)
{
  __shared__ u16 tile[32][33];
  const int tx = threadIdx.x & 31, ty = threadIdx.x >> 5;
  const int bh = blockIdx.z;
  const int t0 = blockIdx.x * 32, d0 = blockIdx.y * 32;
  const u16* ib = in + (size_t)bh * T * DH_;
  u16* ob = out + (size_t)bh * DH_ * T;
#pragma unroll
  for (int j = 0; j < 4; ++j)
    tile[ty + 8 * j][tx] = ib[(size_t)(t0 + ty + 8 * j) * DH_ + d0 + tx];
  __syncthreads();
#pragma unroll
  for (int j = 0; j < 4; ++j)
    ob[(size_t)(d0 + ty + 8 * j) * T + t0 + tx] = tile[tx][ty + 8 * j];
}

__global__ void cvt_bf16(const float* __restrict__ in, u16* __restrict__ out, int n4)
{
  const int i = blockIdx.x * blockDim.x + threadIdx.x;
  if (i < n4) {
    const float4 v = ((const float4*)in)[i];
    uint2 o;
    o.x = packbf2(v.x, v.y);
    o.y = packbf2(v.z, v.w);
    ((uint2*)out)[i] = o;
  }
}

__global__ void mask_bias(const int* __restrict__ mask, float* __restrict__ bias, int n)
{
  const int i = blockIdx.x * blockDim.x + threadIdx.x;
  if (i < n) bias[i] = mask[i] ? 0.f : -1e30f;
}

// ---------------------------------------------------------------------------
extern "C" void kernel_launch(void* const* d_in, const int* in_sizes, int n_in,
                              void* d_out, int out_size, void* d_ws, size_t ws_size,
                              hipStream_t stream)
{
  (void)in_sizes; (void)n_in; (void)out_size; (void)ws_size;
  const float* hidden = (const float*)d_in[0];
  const float* ctx    = (const float*)d_in[1];
  const int*   mask   = (const int*)d_in[2];
  const float* g1 = (const float*)d_in[3];
  const float* b1 = (const float*)d_in[4];
  const float* g2 = (const float*)d_in[5];
  const float* b2 = (const float*)d_in[6];
  const float* g3 = (const float*)d_in[7];
  const float* b3 = (const float*)d_in[8];
  const float* Wq1 = (const float*)d_in[9];
  const float* Wk1 = (const float*)d_in[10];
  const float* Wv1 = (const float*)d_in[11];
  const float* Wo1 = (const float*)d_in[12];
  const float* bo1 = (const float*)d_in[13];
  const float* Wq2 = (const float*)d_in[14];
  const float* Wk2 = (const float*)d_in[15];
  const float* Wv2 = (const float*)d_in[16];
  const float* Wo2 = (const float*)d_in[17];
  const float* bo2 = (const float*)d_in[18];
  const float* Wff1 = (const float*)d_in[19];
  const float* bff1 = (const float*)d_in[20];
  const float* Wff2 = (const float*)d_in[21];
  const float* bff2 = (const float*)d_in[22];

  char* ws = (char*)d_ws;
  size_t off = 0;
  auto alloc = [&](size_t bytes) -> void* {
    void* p = ws + off;
    off += (bytes + 255) & ~(size_t)255;
    return p;
  };
  u16* WqT1  = (u16*)alloc((size_t)1024 * 1024 * 2);
  u16* WkT1  = (u16*)alloc((size_t)1024 * 1024 * 2);
  u16* WvT1  = (u16*)alloc((size_t)1024 * 1024 * 2);
  u16* WoT1  = (u16*)alloc((size_t)1024 * 1024 * 2);
  u16* WqT2  = (u16*)alloc((size_t)1024 * 1024 * 2);
  u16* WkT2  = (u16*)alloc((size_t)1024 * 1024 * 2);
  u16* WvT2  = (u16*)alloc((size_t)1024 * 1024 * 2);
  u16* WoT2  = (u16*)alloc((size_t)1024 * 1024 * 2);
  u16* Wff1T = (u16*)alloc((size_t)8192 * 1024 * 2);
  u16* Wff2T = (u16*)alloc((size_t)1024 * 4096 * 2);
  u16* nbuf  = (u16*)alloc((size_t)M_ * D_ * 2);
  u16* hgbuf = (u16*)alloc((size_t)M_ * FF_ * 2);
  u16* qbuf  = (u16*)alloc((size_t)M_ * D_ * 2);
  u16* kbuf  = (u16*)alloc((size_t)M_ * D_ * 2);
  u16* vbuf  = (u16*)alloc((size_t)M_ * D_ * 2);
  u16* vtbuf = (u16*)alloc((size_t)M_ * D_ * 2);
  u16* attnb = (u16*)alloc((size_t)M_ * D_ * 2);
  u16* ctxb  = (u16*)alloc((size_t)M_ * D_ * 2);
  u16* pbuf  = (u16*)alloc((size_t)4 * M_ * D_ * 2);   // split-K partials (32MB)
  float* biasw = (float*)alloc((size_t)B_ * S_ * 4);
  u16* gbuf = qbuf;            // 32MB alias qbuf..vtbuf; only used in FF phase
  float* hres = (float*)d_out; // residual chain lives in d_out

  const dim3 blk(256);
  const dim3 blk512(512);
  const dim3 gW(32, 32);
  const dim3 gQKV(24, 32);       // 128^2, N=3072 -> 768 blocks
  const dim3 gKV(16, 32);        // 128^2, N=2048 -> 512 blocks
  const dim3 gFFp(16, 16);       // 256^2, N=4096 -> 256 blocks (1/CU exact)
  const dim3 gF2p(4, 16, 4);     // 256^2, N=1024, split-K=4 -> 256 blocks
  const dim3 gS2(8, 32, 2);      // 128^2, N=1024, split-K=2 -> 512 blocks
  const dim3 gA(16, 64);
  const dim3 gV(32, 2, 64);
  const dim3 gR(4096);           // one block per row (N=1024)

  // weight prep
  transpose_w<<<gW, blk, 0, stream>>>(Wq1, WqT1, 1024, 1024);
  transpose_w<<<gW, blk, 0, stream>>>(Wk1, WkT1, 1024, 1024);
  transpose_w<<<gW, blk, 0, stream>>>(Wv1, WvT1, 1024, 1024);
  transpose_w<<<gW, blk, 0, stream>>>(Wo1, WoT1, 1024, 1024);
  transpose_w<<<gW, blk, 0, stream>>>(Wq2, WqT2, 1024, 1024);
  transpose_w<<<gW, blk, 0, stream>>>(Wk2, WkT2, 1024, 1024);
  transpose_w<<<gW, blk, 0, stream>>>(Wv2, WvT2, 1024, 1024);
  transpose_w<<<gW, blk, 0, stream>>>(Wo2, WoT2, 1024, 1024);
  transpose_w<<<dim3(256, 32), blk, 0, stream>>>(Wff1, Wff1T, 1024, 8192);
  transpose_w<<<dim3(32, 128), blk, 0, stream>>>(Wff2, Wff2T, 4096, 1024);
  cvt_bf16<<<dim3((1048576 + 255) / 256), blk, 0, stream>>>(ctx, ctxb, 1048576);
  mask_bias<<<dim3(16), blk, 0, stream>>>(mask, biasw, B_ * S_);

  // --- self attention ---
  ln_kernel<<<dim3(M_), blk, 0, stream>>>(hidden, g1, b1, nbuf);
  gemm128<0><<<gQKV, blk, 0, stream>>>(nbuf, WqT1, nullptr, nullptr, nullptr,
                                       qbuf, M_, 3072, 1024, 16);
  transpose_v<<<gV, blk, 0, stream>>>(vbuf, vtbuf, 1024);
  attn_kernel<false><<<gA, blk, 0, stream>>>(qbuf, kbuf, vtbuf, nullptr, attnb, S_, S_);
  gemm128<4><<<gS2, blk, 0, stream>>>(attnb, WoT1, nullptr, nullptr, nullptr,
                                      pbuf, M_, 1024, 1024, 8);
  reduce_ln<true, 2><<<gR, blk, 0, stream>>>(pbuf, bo1, hidden, hres, g2, b2, nbuf);

  // --- cross attention ---
  gemm128<4><<<gS2, blk, 0, stream>>>(nbuf, WqT2, nullptr, nullptr, nullptr,
                                      pbuf, M_, 1024, 1024, 8);
  reduce_perm<2, true><<<gR, blk, 0, stream>>>(pbuf, qbuf, M_, 1024);
  gemm128<5><<<gKV, blk, 0, stream>>>(ctxb, WkT2, nullptr, nullptr, nullptr,
                                      kbuf, M_, 2048, 1024, 16);
  transpose_v<<<gV, blk, 0, stream>>>(vbuf, vtbuf, 1024);
  attn_kernel<true><<<gA, blk, 0, stream>>>(qbuf, kbuf, vtbuf, biasw, attnb, S_, S_);
  gemm128<4><<<gS2, blk, 0, stream>>>(attnb, WoT2, nullptr, nullptr, nullptr,
                                      pbuf, M_, 1024, 1024, 8);
  reduce_ln<true, 2><<<gR, blk, 0, stream>>>(pbuf, bo2, hres, hres, g3, b3, nbuf);

  // --- GEGLU FF (8-phase deep-ledger 256^2 engine) ---
  gemm256p<2><<<gFFp, blk512, 0, stream>>>(nbuf, Wff1T + (size_t)FF_ * 1024,
                                           bff1 + FF_, nullptr, nullptr, gbuf,
                                           M_, FF_, 1024, 16);
  gemm256p<3><<<gFFp, blk512, 0, stream>>>(nbuf, Wff1T, bff1, nullptr, gbuf,
                                           hgbuf, M_, FF_, 1024, 16);
  gemm256p<4><<<gF2p, blk512, 0, stream>>>(hgbuf, Wff2T, nullptr, nullptr, nullptr,
                                           pbuf, M_, 1024, 4096, 16);
  reduce_ln<false, 4><<<gR, blk, 0, stream>>>(pbuf, bff2, hres, hres, nullptr,
                                              nullptr, nullptr);
}

// Round 11
// 361.441 us; speedup vs baseline: 1.1411x; 1.1411x over previous
//
#include <hip/hip_runtime.h>

typedef unsigned short u16;
typedef unsigned int u32;

#define B_ 4
#define S_ 1024
#define D_ 1024
#define H_ 16
#define DH_ 64
#define FF_ 4096
#define M_ 4096
#define SCALE_ 0.125f

typedef __attribute__((ext_vector_type(8))) __bf16 bf16x8;
typedef __attribute__((ext_vector_type(4))) float f32x4;

__device__ __forceinline__ f32x4 mfma16(bf16x8 a, bf16x8 b, f32x4 c) {
  return __builtin_amdgcn_mfma_f32_16x16x32_bf16(a, b, c, 0, 0, 0);
}

// native converts -> compiler emits v_cvt_pk_bf16_f32 (catalog m240)
__device__ __forceinline__ u16 f2bf(float x) {
  union { __bf16 h; u16 u; } cv; cv.h = (__bf16)x; return cv.u;
}
__device__ __forceinline__ float bf2f(u16 u) {
  union { u32 u; float f; } cv; cv.u = ((u32)u) << 16; return cv.f;
}
__device__ __forceinline__ u32 packbf2(float a, float b) {
  union { u32 u; __bf16 h[2]; } pk;
  pk.h[0] = (__bf16)a; pk.h[1] = (__bf16)b;
  return pk.u;
}
__device__ __forceinline__ float gelu_exact(float x) {
  return 0.5f * x * (1.f + erff(x * 0.7071067811865475f));
}
__device__ __forceinline__ void gload16(const void* g, void* l) {
  __builtin_amdgcn_global_load_lds((__attribute__((address_space(1))) void*)(g),
                                   (__attribute__((address_space(3))) void*)(l),
                                   16, 0, 0);
}

// ===========================================================================
// 128x128 GEMM, 4 waves (2x2), BK=64, dbuf 64KiB LDS — round-6 schedule
// (best measured). Split-K via blockIdx.z (unused this round: z=1). EPI:
//   0 = permuted bf16 -> [ts][B,H,S,DH], ts==0 plane scaled 0.125
//   1 = f32 out = res + acc + bias   (in-place out==res is elementwise-safe)
//   5 = permuted bf16, NO scale (KV fused store)
// ===========================================================================
template<int EPI>
__global__ __launch_bounds__(256, 2) void gemm128(
    const u16* __restrict__ A, const u16* __restrict__ BT,
    const float* __restrict__ bias, const float* __restrict__ res,
    void* __restrict__ out, int M, int N, int K, int ktiles)
{
  __shared__ u16 As[2][128 * 64];
  __shared__ u16 Bs[2][128 * 64];

  const int tid = threadIdx.x;
  const int wave = tid >> 6, lane = tid & 63;
  const int wm = wave >> 1, wn = wave & 1;
  const int qi = lane & 15, g = lane >> 4;

  const int gx = N >> 7;
  const int nwg = gx * (M >> 7);
  int id = blockIdx.y * gridDim.x + blockIdx.x;
  id = (id & 7) * (nwg >> 3) + (id >> 3);      // XCD swizzle (nwg % 8 == 0)
  const int m0 = (id / gx) << 7, n0 = (id % gx) << 7;

  const int NT = ktiles;
  const int kbase = blockIdx.z * ktiles * 64;

  const int r0 = tid >> 3;
  const int scol = (((tid & 7) ^ ((tid >> 3) & 7)) << 3);
  const int swb = wave << 6;

  f32x4 acc[4][4];
#pragma unroll
  for (int i = 0; i < 4; ++i)
#pragma unroll
    for (int j = 0; j < 4; ++j)
      acc[i][j] = (f32x4){0.f, 0.f, 0.f, 0.f};

#define STAGE_A(t, h, b) {                                                  \
    const int tt = (t) >= NT ? (t) - NT : (t);                              \
    _Pragma("unroll")                                                       \
    for (int i = 0; i < 2; ++i) {                                           \
      const int r = (h) * 64 + i * 32 + r0;                                 \
      gload16(A + (size_t)(m0 + r) * K + kbase + tt * 64 + scol,            \
              &As[b][(h) * 4096 + (i * 256 + swb) * 8]);                    \
    } }
#define STAGE_B(t, h, b) {                                                  \
    const int tt = (t) >= NT ? (t) - NT : (t);                              \
    _Pragma("unroll")                                                       \
    for (int i = 0; i < 2; ++i) {                                           \
      const int r = (h) * 64 + i * 32 + r0;                                 \
      gload16(BT + (size_t)(n0 + r) * K + kbase + tt * 64 + scol,           \
              &Bs[b][(h) * 4096 + (i * 256 + swb) * 8]);                    \
    } }

  bf16x8 af[4][2], bfr[4][2];

#define RD_ALL(b)                                                            \
  _Pragma("unroll") for (int mi = 0; mi < 4; ++mi)                           \
  _Pragma("unroll") for (int kk = 0; kk < 2; ++kk) {                         \
    const int row = wm * 64 + mi * 16 + qi;                                  \
    const int cb = ((kk * 64 + (g << 4)) ^ ((qi & 7) << 4));                 \
    af[mi][kk] = *(const bf16x8*)((const char*)&As[b][0] + row * 128 + cb);  \
  }                                                                          \
  _Pragma("unroll") for (int ni = 0; ni < 4; ++ni)                           \
  _Pragma("unroll") for (int kk = 0; kk < 2; ++kk) {                         \
    const int row = wn * 64 + ni * 16 + qi;                                  \
    const int cb = ((kk * 64 + (g << 4)) ^ ((qi & 7) << 4));                 \
    bfr[ni][kk] = *(const bf16x8*)((const char*)&Bs[b][0] + row * 128 + cb); \
  }

#define HALF(milo)                                                           \
  _Pragma("unroll") for (int mi = (milo); mi < (milo) + 2; ++mi)             \
  _Pragma("unroll") for (int ni = 0; ni < 4; ++ni)                           \
  _Pragma("unroll") for (int kk = 0; kk < 2; ++kk)                           \
    acc[mi][ni] = mfma16(af[mi][kk], bfr[ni][kk], acc[mi][ni]);

#define BAR() __builtin_amdgcn_s_barrier()
#define LGKM0() { asm volatile("s_waitcnt lgkmcnt(0)" ::: "memory");         \
                  __builtin_amdgcn_sched_barrier(0); }
#define VM8() asm volatile("s_waitcnt vmcnt(8)" ::: "memory")
#define PRIO(x) __builtin_amdgcn_s_setprio(x)

  STAGE_A(0, 0, 0); STAGE_A(0, 1, 0); STAGE_B(0, 0, 0); STAGE_B(0, 1, 0);
  STAGE_A(1, 0, 1); STAGE_A(1, 1, 1); STAGE_B(1, 0, 1); STAGE_B(1, 1, 1);
  VM8();
  BAR();

  const int NI = NT >> 1;
  for (int it = 0; it < NI; ++it) {
    const int k = it * 2;
    RD_ALL(0); LGKM0();
    BAR();
    STAGE_A(k + 2, 0, 0); STAGE_A(k + 2, 1, 0);
    PRIO(1); HALF(0); PRIO(0);
    STAGE_B(k + 2, 0, 0); STAGE_B(k + 2, 1, 0);
    PRIO(1); HALF(2); PRIO(0);
    VM8();
    BAR();
    RD_ALL(1); LGKM0();
    BAR();
    STAGE_A(k + 3, 0, 1); STAGE_A(k + 3, 1, 1);
    PRIO(1); HALF(0); PRIO(0);
    STAGE_B(k + 3, 0, 1); STAGE_B(k + 3, 1, 1);
    PRIO(1); HALF(2); PRIO(0);
    VM8();
    BAR();
  }

#pragma unroll
  for (int mi = 0; mi < 4; ++mi) {
#pragma unroll
    for (int ni = 0; ni < 4; ++ni) {
#pragma unroll
      for (int r = 0; r < 4; ++r) {
        const int m = m0 + wm * 64 + mi * 16 + g * 4 + r;
        const int n = n0 + wn * 64 + ni * 16 + qi;
        float v = acc[mi][ni][r];
        if (EPI == 0 || EPI == 5) {
          const int ts = n >> 10, b = m >> 10, s = m & 1023;
          const int hh = (n >> 6) & 15, dh = n & 63;
          if (EPI == 0 && ts == 0) v *= SCALE_;
          ((u16*)out)[(size_t)ts * (B_ * H_ * S_ * DH_) +
                      (((size_t)(b * H_ + hh) * S_) + s) * DH_ + dh] = f2bf(v);
        } else {
          const size_t idx = (size_t)m * N + n;
          ((float*)out)[idx] = res[idx] + v + bias[n];
        }
      }
    }
  }
#undef STAGE_A
#undef STAGE_B
#undef RD_ALL
#undef HALF
#undef BAR
#undef LGKM0
#undef VM8
#undef PRIO
}

// ===========================================================================
// Merged GEGLU FF1: C_h = A x BTh^T, C_g = A x BTg^T over the SAME A-tile;
// out[m][n] = (C_h + bias[n]) * gelu(C_g + bias[FF+n]).  128x128 tile,
// 4 waves (2x2), BK=64, single-buffered 48 KiB LDS (A,Bh,Bg), 2 blocks/CU.
// Eliminates one dispatch's A-staging and the 64MB gbuf round-trip.
// bfr reloaded between h/g halves to cap VGPR (~200).
// ===========================================================================
__global__ __launch_bounds__(256, 2) void ffgeglu(
    const u16* __restrict__ A, const u16* __restrict__ BTh,
    const u16* __restrict__ BTg, const float* __restrict__ bias,
    u16* __restrict__ out)
{
  __shared__ u16 As[128 * 64];
  __shared__ u16 Bhs[128 * 64];
  __shared__ u16 Bgs[128 * 64];

  const int tid = threadIdx.x;
  const int wave = tid >> 6, lane = tid & 63;
  const int wm = wave >> 1, wn = wave & 1;
  const int qi = lane & 15, g = lane >> 4;

  const int gx = 32;                       // N=4096 / 128
  const int nwg = 1024;
  int id = blockIdx.y * gridDim.x + blockIdx.x;
  id = (id & 7) * (nwg >> 3) + (id >> 3);  // XCD swizzle
  const int m0 = (id / gx) << 7, n0 = (id % gx) << 7;
  const int K = 1024;

  const int r0 = tid >> 3;
  const int scol = (((tid & 7) ^ ((tid >> 3) & 7)) << 3);
  const int swb = wave << 6;

  f32x4 acch[4][4], accg[4][4];
#pragma unroll
  for (int i = 0; i < 4; ++i)
#pragma unroll
    for (int j = 0; j < 4; ++j) {
      acch[i][j] = (f32x4){0.f, 0.f, 0.f, 0.f};
      accg[i][j] = (f32x4){0.f, 0.f, 0.f, 0.f};
    }

  for (int t = 0; t < 16; ++t) {
    if (t) __syncthreads();
#pragma unroll
    for (int i = 0; i < 4; ++i) {
      const int r = i * 32 + r0;
      gload16(A + (size_t)(m0 + r) * K + t * 64 + scol,
              &As[(i * 256 + swb) * 8]);
    }
#pragma unroll
    for (int i = 0; i < 4; ++i) {
      const int r = i * 32 + r0;
      gload16(BTh + (size_t)(n0 + r) * K + t * 64 + scol,
              &Bhs[(i * 256 + swb) * 8]);
    }
#pragma unroll
    for (int i = 0; i < 4; ++i) {
      const int r = i * 32 + r0;
      gload16(BTg + (size_t)(n0 + r) * K + t * 64 + scol,
              &Bgs[(i * 256 + swb) * 8]);
    }
    __syncthreads();

    bf16x8 af[4][2], bfr[4][2];
#pragma unroll
    for (int mi = 0; mi < 4; ++mi)
#pragma unroll
      for (int kk = 0; kk < 2; ++kk) {
        const int row = wm * 64 + mi * 16 + qi;
        const int cb = ((kk * 64 + (g << 4)) ^ ((qi & 7) << 4));
        af[mi][kk] = *(const bf16x8*)((const char*)&As[0] + row * 128 + cb);
      }
    // ---- h half ----
#pragma unroll
    for (int ni = 0; ni < 4; ++ni)
#pragma unroll
      for (int kk = 0; kk < 2; ++kk) {
        const int row = wn * 64 + ni * 16 + qi;
        const int cb = ((kk * 64 + (g << 4)) ^ ((qi & 7) << 4));
        bfr[ni][kk] = *(const bf16x8*)((const char*)&Bhs[0] + row * 128 + cb);
      }
#pragma unroll
    for (int mi = 0; mi < 4; ++mi)
#pragma unroll
      for (int ni = 0; ni < 4; ++ni)
#pragma unroll
        for (int kk = 0; kk < 2; ++kk)
          acch[mi][ni] = mfma16(af[mi][kk], bfr[ni][kk], acch[mi][ni]);
    // ---- gate half (bfr reused) ----
#pragma unroll
    for (int ni = 0; ni < 4; ++ni)
#pragma unroll
      for (int kk = 0; kk < 2; ++kk) {
        const int row = wn * 64 + ni * 16 + qi;
        const int cb = ((kk * 64 + (g << 4)) ^ ((qi & 7) << 4));
        bfr[ni][kk] = *(const bf16x8*)((const char*)&Bgs[0] + row * 128 + cb);
      }
#pragma unroll
    for (int mi = 0; mi < 4; ++mi)
#pragma unroll
      for (int ni = 0; ni < 4; ++ni)
#pragma unroll
        for (int kk = 0; kk < 2; ++kk)
          accg[mi][ni] = mfma16(af[mi][kk], bfr[ni][kk], accg[mi][ni]);
  }

#pragma unroll
  for (int mi = 0; mi < 4; ++mi) {
#pragma unroll
    for (int ni = 0; ni < 4; ++ni) {
#pragma unroll
      for (int r = 0; r < 4; ++r) {
        const int m = m0 + wm * 64 + mi * 16 + g * 4 + r;
        const int n = n0 + wn * 64 + ni * 16 + qi;
        const float hv = acch[mi][ni][r] + bias[n];
        const float gv = accg[mi][ni][r] + bias[FF_ + n];
        out[(size_t)m * FF_ + n] = f2bf(hv * gelu_exact(gv));
      }
    }
  }
}

// ---------------------------------------------------------------------------
// Flash attention. Q pre-scaled by 0.125. Fixed-max softmax (scores bounded;
// masked scores = -1e30 -> exp = 0). Direct LDS staging. 4 waves x 16 q-rows.
// ---------------------------------------------------------------------------
template<bool MASKED>
__global__ __launch_bounds__(256, 4) void attn_kernel(
    const u16* __restrict__ Q, const u16* __restrict__ Kb,
    const u16* __restrict__ VT, const float* __restrict__ bias,
    u16* __restrict__ O, int S, int T)
{
  __shared__ u16 Ks[64 * 72];
  __shared__ u16 VTs[64 * 72];
  __shared__ u16 Ps[4][16 * 72];
  __shared__ float biasS[64];

  const int bh = blockIdx.y;
  const int b = bh >> 4, h = bh & 15;
  const int tid = threadIdx.x;
  const int wave = tid >> 6, lane = tid & 63;
  const int g = lane >> 4, qi = lane & 15;
  const int q0w = blockIdx.x * 64 + wave * 16;

  const u16* Qb = Q + (size_t)bh * S * DH_;
  const u16* Kg = Kb + (size_t)bh * T * DH_;
  const u16* Vg = VT + (size_t)bh * DH_ * T;

  bf16x8 qf[2];
  qf[0] = *(const bf16x8*)&Qb[(q0w + qi) * DH_ + g * 8];
  qf[1] = *(const bf16x8*)&Qb[(q0w + qi) * DH_ + 32 + g * 8];

  f32x4 acc[4];
#pragma unroll
  for (int i = 0; i < 4; ++i) acc[i] = (f32x4){0.f, 0.f, 0.f, 0.f};
  float l_run = 1e-30f;

  u16* Pw = &Ps[wave][0];

  for (int t0 = 0; t0 < T; t0 += 64) {
    __syncthreads();
#pragma unroll
    for (int i = 0; i < 2; ++i) {
      const int flat = i * 256 + tid;
      const int row = flat >> 3, kc = flat & 7;
      *(uint4*)&Ks[row * 72 + kc * 8] = *(const uint4*)&Kg[(size_t)(t0 + row) * DH_ + kc * 8];
      *(uint4*)&VTs[row * 72 + kc * 8] = *(const uint4*)&Vg[(size_t)row * T + t0 + kc * 8];
    }
    if (MASKED && tid < 64) biasS[tid] = bias[b * T + t0 + tid];
    __syncthreads();

    f32x4 sacc[4];
#pragma unroll
    for (int nt = 0; nt < 4; ++nt) sacc[nt] = (f32x4){0.f, 0.f, 0.f, 0.f};
#pragma unroll
    for (int kk = 0; kk < 2; ++kk) {
#pragma unroll
      for (int nt = 0; nt < 4; ++nt) {
        bf16x8 kf = *(const bf16x8*)&Ks[(nt * 16 + qi) * 72 + kk * 32 + g * 8];
        sacc[nt] = mfma16(kf, qf[kk], sacc[nt]);
      }
    }
    float p[4][4];
    float lsum = 0.f;
#pragma unroll
    for (int nt = 0; nt < 4; ++nt)
#pragma unroll
      for (int r = 0; r < 4; ++r) {
        float v = sacc[nt][r];
        if (MASKED) v += biasS[nt * 16 + g * 4 + r];
        const float e = __expf(v);
        p[nt][r] = e;
        lsum += e;
      }
    lsum += __shfl_xor(lsum, 16);
    lsum += __shfl_xor(lsum, 32);
    l_run += lsum;

#pragma unroll
    for (int nt = 0; nt < 4; ++nt) {
      uint2 w;
      w.x = packbf2(p[nt][0], p[nt][1]);
      w.y = packbf2(p[nt][2], p[nt][3]);
      *(uint2*)&Pw[qi * 72 + nt * 16 + g * 4] = w;
    }

#pragma unroll
    for (int kk = 0; kk < 2; ++kk) {
      bf16x8 pf = *(const bf16x8*)&Pw[qi * 72 + kk * 32 + g * 8];
#pragma unroll
      for (int ndh = 0; ndh < 4; ++ndh) {
        bf16x8 vf = *(const bf16x8*)&VTs[(ndh * 16 + qi) * 72 + kk * 32 + g * 8];
        acc[ndh] = mfma16(vf, pf, acc[ndh]);
      }
    }
  }

  const float inv = 1.f / l_run;
  const int qg = q0w + qi;
#pragma unroll
  for (int ndh = 0; ndh < 4; ++ndh) {
    uint2 w;
    w.x = packbf2(acc[ndh][0] * inv, acc[ndh][1] * inv);
    w.y = packbf2(acc[ndh][2] * inv, acc[ndh][3] * inv);
    *(uint2*)&O[(size_t)(b * S_ + qg) * D_ + h * DH_ + ndh * 16 + g * 4] = w;
  }
}

// ---------------------------------------------------------------------------
__global__ __launch_bounds__(256) void ln_kernel(
    const float* __restrict__ x, const float* __restrict__ gg,
    const float* __restrict__ bb, u16* __restrict__ out)
{
  __shared__ float red[8];
  const int row = blockIdx.x, tid = threadIdx.x;
  const float4 v = ((const float4*)(x + (size_t)row * D_))[tid];
  float s = v.x + v.y + v.z + v.w;
  float sq = v.x * v.x + v.y * v.y + v.z * v.z + v.w * v.w;
#pragma unroll
  for (int m = 32; m; m >>= 1) {
    s += __shfl_xor(s, m);
    sq += __shfl_xor(sq, m);
  }
  const int wave = tid >> 6, lane = tid & 63;
  if (lane == 0) { red[wave * 2] = s; red[wave * 2 + 1] = sq; }
  __syncthreads();
  const float St = red[0] + red[2] + red[4] + red[6];
  const float SQt = red[1] + red[3] + red[5] + red[7];
  const float mean = St * (1.f / 1024.f);
  float var = SQt * (1.f / 1024.f) - mean * mean;
  var = fmaxf(var, 0.f);
  const float rinv = rsqrtf(var + 1e-12f);
  const float4 g4 = ((const float4*)gg)[tid];
  const float4 b4 = ((const float4*)bb)[tid];
  uint2 o;
  o.x = packbf2((v.x - mean) * rinv * g4.x + b4.x, (v.y - mean) * rinv * g4.y + b4.y);
  o.y = packbf2((v.z - mean) * rinv * g4.z + b4.z, (v.w - mean) * rinv * g4.w + b4.w);
  ((uint2*)(out + (size_t)row * D_))[tid] = o;
}

// single 1024x1024 f32->bf16 transpose (for big FF weights)
__global__ __launch_bounds__(256) void transpose_w(
    const float* __restrict__ in, u16* __restrict__ out, int K, int N)
{
  __shared__ float tile[32][33];
  const int tx = threadIdx.x & 31, ty = threadIdx.x >> 5;
  const int k0 = blockIdx.y * 32, n0 = blockIdx.x * 32;
#pragma unroll
  for (int j = 0; j < 4; ++j)
    tile[ty + 8 * j][tx] = in[(size_t)(k0 + ty + 8 * j) * N + n0 + tx];
  __syncthreads();
#pragma unroll
  for (int j = 0; j < 4; ++j)
    out[(size_t)(n0 + ty + 8 * j) * K + k0 + tx] = f2bf(tile[tx][ty + 8 * j]);
}

// batched: 8 x (1024x1024) transposes, z selects weight; outs contiguous
__global__ __launch_bounds__(256) void transpose_w8(
    const float* __restrict__ w0, const float* __restrict__ w1,
    const float* __restrict__ w2, const float* __restrict__ w3,
    const float* __restrict__ w4, const float* __restrict__ w5,
    const float* __restrict__ w6, const float* __restrict__ w7,
    u16* __restrict__ outbase)
{
  __shared__ float tile[32][33];
  const float* srcs[8] = {w0, w1, w2, w3, w4, w5, w6, w7};
  const float* in = srcs[blockIdx.z];
  u16* out = outbase + (size_t)blockIdx.z * 1024 * 1024;
  const int tx = threadIdx.x & 31, ty = threadIdx.x >> 5;
  const int k0 = blockIdx.y * 32, n0 = blockIdx.x * 32;
#pragma unroll
  for (int j = 0; j < 4; ++j)
    tile[ty + 8 * j][tx] = in[(size_t)(k0 + ty + 8 * j) * 1024 + n0 + tx];
  __syncthreads();
#pragma unroll
  for (int j = 0; j < 4; ++j)
    out[(size_t)(n0 + ty + 8 * j) * 1024 + k0 + tx] = f2bf(tile[tx][ty + 8 * j]);
}

__global__ __launch_bounds__(256) void transpose_v(
    const u16* __restrict__ in, u16* __restrict__ out, int T)
{
  __shared__ u16 tile[32][33];
  const int tx = threadIdx.x & 31, ty = threadIdx.x >> 5;
  const int bh = blockIdx.z;
  const int t0 = blockIdx.x * 32, d0 = blockIdx.y * 32;
  const u16* ib = in + (size_t)bh * T * DH_;
  u16* ob = out + (size_t)bh * DH_ * T;
#pragma unroll
  for (int j = 0; j < 4; ++j)
    tile[ty + 8 * j][tx] = ib[(size_t)(t0 + ty + 8 * j) * DH_ + d0 + tx];
  __syncthreads();
#pragma unroll
  for (int j = 0; j < 4; ++j)
    ob[(size_t)(d0 + ty + 8 * j) * T + t0 + tx] = tile[tx][ty + 8 * j];
}

__global__ void cvt_bf16(const float* __restrict__ in, u16* __restrict__ out, int n4)
{
  const int i = blockIdx.x * blockDim.x + threadIdx.x;
  if (i < n4) {
    const float4 v = ((const float4*)in)[i];
    uint2 o;
    o.x = packbf2(v.x, v.y);
    o.y = packbf2(v.z, v.w);
    ((uint2*)out)[i] = o;
  }
}

__global__ void mask_bias(const int* __restrict__ mask, float* __restrict__ bias, int n)
{
  const int i = blockIdx.x * blockDim.x + threadIdx.x;
  if (i < n) bias[i] = mask[i] ? 0.f : -1e30f;
}

// ---------------------------------------------------------------------------
extern "C" void kernel_launch(void* const* d_in, const int* in_sizes, int n_in,
                              void* d_out, int out_size, void* d_ws, size_t ws_size,
                              hipStream_t stream)
{
  (void)in_sizes; (void)n_in; (void)out_size; (void)ws_size;
  const float* hidden = (const float*)d_in[0];
  const float* ctx    = (const float*)d_in[1];
  const int*   mask   = (const int*)d_in[2];
  const float* g1 = (const float*)d_in[3];
  const float* b1 = (const float*)d_in[4];
  const float* g2 = (const float*)d_in[5];
  const float* b2 = (const float*)d_in[6];
  const float* g3 = (const float*)d_in[7];
  const float* b3 = (const float*)d_in[8];
  const float* Wq1 = (const float*)d_in[9];
  const float* Wk1 = (const float*)d_in[10];
  const float* Wv1 = (const float*)d_in[11];
  const float* Wo1 = (const float*)d_in[12];
  const float* bo1 = (const float*)d_in[13];
  const float* Wq2 = (const float*)d_in[14];
  const float* Wk2 = (const float*)d_in[15];
  const float* Wv2 = (const float*)d_in[16];
  const float* Wo2 = (const float*)d_in[17];
  const float* bo2 = (const float*)d_in[18];
  const float* Wff1 = (const float*)d_in[19];
  const float* bff1 = (const float*)d_in[20];
  const float* Wff2 = (const float*)d_in[21];
  const float* bff2 = (const float*)d_in[22];

  char* ws = (char*)d_ws;
  size_t off = 0;
  auto alloc = [&](size_t bytes) -> void* {
    void* p = ws + off;
    off += (bytes + 255) & ~(size_t)255;
    return p;
  };
  // WqT1..WoT2 are 8 CONTIGUOUS 2MB blocks (transpose_w8 target).
  // WqT1/WkT1/WvT1 contiguous (fused QKV B); WkT2/WvT2 contiguous (KV B);
  // qbuf/kbuf/vbuf contiguous (fused permuted-store targets).
  u16* WqT1  = (u16*)alloc((size_t)1024 * 1024 * 2);
  u16* WkT1  = (u16*)alloc((size_t)1024 * 1024 * 2);
  u16* WvT1  = (u16*)alloc((size_t)1024 * 1024 * 2);
  u16* WoT1  = (u16*)alloc((size_t)1024 * 1024 * 2);
  u16* WqT2  = (u16*)alloc((size_t)1024 * 1024 * 2);
  u16* WkT2  = (u16*)alloc((size_t)1024 * 1024 * 2);
  u16* WvT2  = (u16*)alloc((size_t)1024 * 1024 * 2);
  u16* WoT2  = (u16*)alloc((size_t)1024 * 1024 * 2);
  u16* Wff1T = (u16*)alloc((size_t)8192 * 1024 * 2);
  u16* Wff2T = (u16*)alloc((size_t)1024 * 4096 * 2);
  u16* nbuf  = (u16*)alloc((size_t)M_ * D_ * 2);
  u16* hgbuf = (u16*)alloc((size_t)M_ * FF_ * 2);
  u16* qbuf  = (u16*)alloc((size_t)M_ * D_ * 2);
  u16* kbuf  = (u16*)alloc((size_t)M_ * D_ * 2);
  u16* vbuf  = (u16*)alloc((size_t)M_ * D_ * 2);
  u16* vtbuf = (u16*)alloc((size_t)M_ * D_ * 2);
  u16* attnb = (u16*)alloc((size_t)M_ * D_ * 2);
  u16* ctxb  = (u16*)alloc((size_t)M_ * D_ * 2);
  float* biasw = (float*)alloc((size_t)B_ * S_ * 4);
  float* hres = (float*)d_out;   // residual chain lives in d_out (f32)
  (void)WkT1; (void)WvT1; (void)WkT2; (void)WvT2; (void)WoT2;

  const dim3 blk(256);
  const dim3 gW8(32, 32, 8);
  const dim3 gQKV(24, 32);       // N=3072 -> 768 blocks
  const dim3 gKV(16, 32);        // N=2048 -> 512 blocks
  const dim3 gP(8, 32);          // N=1024 -> 256 blocks (direct, no split-K)
  const dim3 gFF(32, 32);        // merged GEGLU: 1024 blocks
  const dim3 gA(16, 64);
  const dim3 gV(32, 2, 64);

  // weight prep (batched)
  transpose_w8<<<gW8, blk, 0, stream>>>(Wq1, Wk1, Wv1, Wo1, Wq2, Wk2, Wv2, Wo2,
                                        WqT1);
  transpose_w<<<dim3(256, 32), blk, 0, stream>>>(Wff1, Wff1T, 1024, 8192);
  transpose_w<<<dim3(32, 128), blk, 0, stream>>>(Wff2, Wff2T, 4096, 1024);
  cvt_bf16<<<dim3(4096), blk, 0, stream>>>(ctx, ctxb, 1048576);
  mask_bias<<<dim3(16), blk, 0, stream>>>(mask, biasw, B_ * S_);

  // --- self attention ---
  ln_kernel<<<dim3(M_), blk, 0, stream>>>(hidden, g1, b1, nbuf);
  gemm128<0><<<gQKV, blk, 0, stream>>>(nbuf, WqT1, nullptr, nullptr,
                                       qbuf, M_, 3072, 1024, 16);
  transpose_v<<<gV, blk, 0, stream>>>(vbuf, vtbuf, 1024);
  attn_kernel<false><<<gA, blk, 0, stream>>>(qbuf, kbuf, vtbuf, nullptr, attnb,
                                             S_, S_);
  // h1 = hidden + attnO + bo1 (direct, f32 into d_out)
  gemm128<1><<<gP, blk, 0, stream>>>(attnb, WoT1, bo1, hidden,
                                     hres, M_, 1024, 1024, 16);
  ln_kernel<<<dim3(M_), blk, 0, stream>>>(hres, g2, b2, nbuf);

  // --- cross attention ---
  gemm128<0><<<gP, blk, 0, stream>>>(nbuf, WqT2, nullptr, nullptr,
                                     qbuf, M_, 1024, 1024, 16);   // Q2 (scaled)
  gemm128<5><<<gKV, blk, 0, stream>>>(ctxb, WkT2, nullptr, nullptr,
                                      kbuf, M_, 2048, 1024, 16);  // K2,V2 fused
  transpose_v<<<gV, blk, 0, stream>>>(vbuf, vtbuf, 1024);
  attn_kernel<true><<<gA, blk, 0, stream>>>(qbuf, kbuf, vtbuf, biasw, attnb,
                                            S_, S_);
  // h2 = h1 + attnO + bo2 (in-place on d_out; elementwise-safe)
  gemm128<1><<<gP, blk, 0, stream>>>(attnb, WoT2, bo2, hres,
                                     hres, M_, 1024, 1024, 16);
  ln_kernel<<<dim3(M_), blk, 0, stream>>>(hres, g3, b3, nbuf);

  // --- GEGLU FF ---
  ffgeglu<<<gFF, blk, 0, stream>>>(nbuf, Wff1T, Wff1T + (size_t)FF_ * 1024,
                                   bff1, hgbuf);
  // out = h2 + (hg @ Wff2) + bff2 (direct, in-place on d_out)
  gemm128<1><<<gP, blk, 0, stream>>>(hgbuf, Wff2T, bff2, hres,
                                     hres, M_, 1024, 4096, 64);
}